// Round 3
// baseline (7564.401 us; speedup 1.0000x reference)
//
#include <hip/hip_runtime.h>
#include <hip/hip_bf16.h>

// B=64, T=512, D=512, H=512, 3H=1536. fp32 I/O; bf16 MFMA operands.
#define B_ 64
#define T_ 512
#define D_ 512
#define H_ 512
#define G3 1536
#define NBLK 16          // persistent blocks: 96 gate-cols + 4 samples each

typedef float f32x4 __attribute__((ext_vector_type(4)));
typedef __bf16 bf16x8 __attribute__((ext_vector_type(8)));
typedef unsigned long long qword;

#define LDSP 56          // k1 LDS pitch
#define WPITCH 520       // persistent-kernel w-slice pitch (bf16 elems): breaks bank conflicts

union bfpack { bf16x8 v; __hip_bfloat16 h[8]; };
union q2bf { qword q[2]; bf16x8 v; };            // two coherent 8B loads -> one MFMA A-frag
union qbf4 { qword q; __hip_bfloat16 h[4]; };    // 8B <-> 4 bf16

__device__ inline bf16x8 cvt8(const float* __restrict__ p) {
    float4 f0 = *(const float4*)p;
    float4 f1 = *(const float4*)(p + 4);
    bfpack u;
    u.h[0] = __float2bfloat16(f0.x); u.h[1] = __float2bfloat16(f0.y);
    u.h[2] = __float2bfloat16(f0.z); u.h[3] = __float2bfloat16(f0.w);
    u.h[4] = __float2bfloat16(f1.x); u.h[5] = __float2bfloat16(f1.y);
    u.h[6] = __float2bfloat16(f1.z); u.h[7] = __float2bfloat16(f1.w);
    return u.v;
}

// Coherent (memory-side) helpers: relaxed agent-scope atomics lower to sc0/sc1
// flagged global ops (L1/L2 bypass), no wbl2/inv fences.
__device__ inline qword ld_coh(const qword* p) {
    return __hip_atomic_load(p, __ATOMIC_RELAXED, __HIP_MEMORY_SCOPE_AGENT);
}
__device__ inline unsigned int ld_coh32(const unsigned int* p) {
    return __hip_atomic_load(p, __ATOMIC_RELAXED, __HIP_MEMORY_SCOPE_AGENT);
}
__device__ inline void st_coh64(qword* p, qword v) {
    __hip_atomic_store(p, v, __ATOMIC_RELAXED, __HIP_MEMORY_SCOPE_AGENT);
}
__device__ inline void st_coh32(unsigned int* p, unsigned int v) {
    __hip_atomic_store(p, v, __ATOMIC_RELAXED, __HIP_MEMORY_SCOPE_AGENT);
}

// Tagged HG pair: {bf16 col2p, bf16 col2p+1, u32 tag} in one 8B word.
// Single-copy-atomic store/load => data+sync fused, no drain/flag/barrier.
__device__ inline qword pack_hg(float a, float b, unsigned int tag) {
    union { __hip_bfloat16 h; unsigned short u; } ua, ub;
    ua.h = __float2bfloat16(a); ub.h = __float2bfloat16(b);
    return (qword)((unsigned int)ua.u | ((unsigned int)ub.u << 16)) | ((qword)tag << 32);
}
__device__ inline float hg_lo(qword q) {
    union { unsigned short u; __hip_bfloat16 h; } x;
    x.u = (unsigned short)(q & 0xffffu);
    return __bfloat162float(x.h);
}
__device__ inline float hg_hi(qword q) {
    union { unsigned short u; __hip_bfloat16 h; } x;
    x.u = (unsigned short)((q >> 16) & 0xffffu);
    return __bfloat162float(x.h);
}

// ---------------- K0: init HB (h bf16), zero HG tags, flags=1 ----------------
__global__ void k0_init(const float* __restrict__ h_in,
                        __hip_bfloat16* __restrict__ hb,
                        qword* __restrict__ hgp,
                        unsigned int* __restrict__ flags) {
    int i = blockIdx.x * blockDim.x + threadIdx.x;
    if (i < B_ * H_) hb[i] = __float2bfloat16(h_in[i]);
    for (int k = i; k < 64 * 768; k += 32768) hgp[k] = 0ull;   // clear tags
    if (i < NBLK) flags[i] = 1u;                                // h_0 ready
}

// ---------------- K1: XG = x @ w_ih^T + b_ih (MFMA 128x128, bf16 out) --------
__global__ __launch_bounds__(256) void k1_xgemm(
    const float* __restrict__ X, const float* __restrict__ W,
    const float* __restrict__ bias, __hip_bfloat16* __restrict__ XG)
{
    __shared__ __align__(16) __hip_bfloat16 la[128 * LDSP];
    __shared__ __align__(16) __hip_bfloat16 lb[128 * LDSP];
    int tid = threadIdx.x, bx = blockIdx.x;
    int m0 = (bx / 12) * 128, n0 = (bx % 12) * 128;
    int wave = tid >> 6, lane = tid & 63;
    int wh = wave >> 1, ww = wave & 1;
    int l15 = lane & 15, kq = lane >> 4;

    f32x4 acc[4][4];
    #pragma unroll
    for (int i = 0; i < 4; i++)
        #pragma unroll
        for (int j = 0; j < 4; j++) acc[i][j] = (f32x4){0.f, 0.f, 0.f, 0.f};

    for (int kt = 0; kt < 16; ++kt) {
        int k0 = kt * 32;
        for (int s = tid; s < 512; s += 256) {
            int r = s >> 2, c = s & 3;
            *(bf16x8*)&la[r * LDSP + c * 8] = cvt8(&X[(size_t)(m0 + r) * D_ + k0 + c * 8]);
            *(bf16x8*)&lb[r * LDSP + c * 8] = cvt8(&W[(size_t)(n0 + r) * D_ + k0 + c * 8]);
        }
        __syncthreads();
        bf16x8 af[4], bq[4];
        #pragma unroll
        for (int i = 0; i < 4; i++)
            af[i] = *(const bf16x8*)&la[(wh * 64 + i * 16 + l15) * LDSP + kq * 8];
        #pragma unroll
        for (int j = 0; j < 4; j++)
            bq[j] = *(const bf16x8*)&lb[(ww * 64 + j * 16 + l15) * LDSP + kq * 8];
        #pragma unroll
        for (int i = 0; i < 4; i++)
            #pragma unroll
            for (int j = 0; j < 4; j++)
                acc[i][j] = __builtin_amdgcn_mfma_f32_16x16x32_bf16(af[i], bq[j], acc[i][j], 0, 0, 0);
        __syncthreads();
    }
    #pragma unroll
    for (int i = 0; i < 4; i++)
        #pragma unroll
        for (int j = 0; j < 4; j++)
            #pragma unroll
            for (int r = 0; r < 4; r++) {
                int m = m0 + wh * 64 + i * 16 + kq * 4 + r;
                int n = n0 + ww * 64 + j * 16 + l15;
                int b = m >> 9, t = m & 511;
                XG[((size_t)t * B_ + b) * G3 + n] = __float2bfloat16(acc[i][j][r] + bias[n]);
            }
}

// ---------------- K2: persistent recurrence kernel ---------------------------
// 16 blocks x 512 threads. Block i: GEMM cols [96i,96i+96); pointwise samples
// [4i,4i+4) (thread owns 4 contiguous cols). Two exchanges per step:
//   HG: tagged 8B pairs {2 x bf16, tag=t+1} -> consumers poll data directly
//       (no drain, no flag, no barrier).
//   HB: plain bf16 + per-block monotone flag (drain via __syncthreads, then
//       tid0 publishes flag=t+2; GEMM polls flags >= t+1 before A-frag loads).
__global__ __launch_bounds__(512, 1) void k2_recur(
    const float* __restrict__ h_in, const float* __restrict__ Whh,
    const float* __restrict__ b_hh,
    const float* __restrict__ lnrw, const float* __restrict__ lnrb,
    const float* __restrict__ lnzw, const float* __restrict__ lnzb,
    const float* __restrict__ lnnw, const float* __restrict__ lnnb,
    const __hip_bfloat16* __restrict__ XG,
    qword* __restrict__ HGP, __hip_bfloat16* __restrict__ HB,
    unsigned int* __restrict__ flags, float* __restrict__ out)
{
    __shared__ __align__(16) __hip_bfloat16 lw[96 * WPITCH]; // 99,840 B
    __shared__ float sc[32];

    const int tid = threadIdx.x;
    const int blk = blockIdx.x;
    const int n0 = blk * 96;   // gate-column slice base
    const int s0 = blk * 4;    // pointwise sample base

    // --- one-time: stage w_hh slice fp32->bf16 into LDS (pitch WPITCH) ---
    for (int idx = tid; idx < 96 * 64; idx += 512) {
        int row = idx >> 6, ch = idx & 63;
        *(bf16x8*)&lw[row * WPITCH + ch * 8] = cvt8(&Whh[(size_t)(n0 + row) * H_ + ch * 8]);
    }

    // --- GEMM wave roles ---
    const int w = tid >> 6, lane = tid & 63;
    const int l15 = lane & 15, kq = lane >> 4;
    const int mt = w >> 1;             // m-tile 0..3 (rows mt*16+l15)
    const int nj0 = (w & 1) * 3;       // 3 n-tiles per wave
    const bool evenl = (l15 & 1) == 0;

    // --- pointwise roles: sample sid, 4 CONTIGUOUS cols 4c..4c+3 ---
    const int sid = tid >> 7;          // 0..3
    const int c = tid & 127;
    const int b = s0 + sid;

    // per-thread constant preloads (stay in regs across the t-loop)
    float bhr[4], bhz[4], bhn[4], wr[4], br_[4], wz[4], bz_[4], wn[4], bn_[4], hf[4];
    #pragma unroll
    for (int j = 0; j < 4; j++) {
        int col = 4 * c + j;
        bhr[j] = b_hh[col];       bhz[j] = b_hh[512 + col]; bhn[j] = b_hh[1024 + col];
        wr[j] = lnrw[col]; br_[j] = lnrb[col];
        wz[j] = lnzw[col]; bz_[j] = lnzb[col];
        wn[j] = lnnw[col]; bn_[j] = lnnb[col];
        hf[j] = h_in[b * H_ + col];   // fp32 h shadow (this block owns sample b, cols 4c..4c+3)
    }
    __syncthreads();

    const float inv = 1.0f / 512.0f;
    // HB row base in 8B units: row*(512 bf16)=128 qwords; lane frag at kq*8 bf16 = kq*2 qwords
    const qword* hbq_base = (const qword*)HB + (size_t)(mt * 16 + l15) * 128 + kq * 2;
    const qword* hg_mine = HGP + (size_t)b * 768 + 2 * c;   // pair base for this thread

    for (int t = 0; t < T_; ++t) {
        const unsigned int tag = (unsigned int)(t + 1);

        // ---- XG preload for this step (plain cached loads; no cross-step hazard)
        const qword* xgq = (const qword*)(XG + ((size_t)t * B_ + b) * G3) + c;
        qbf4 xr8, xz8, xn8;
        xr8.q = xgq[0];            // r-gate cols 4c..4c+3
        xz8.q = xgq[128];          // z-gate
        xn8.q = xgq[256];          // n-gate

        // ---- wait for h_t (flags[i] >= t+1), wave-local poll ----
        {
            int spins = 0;
            for (;;) {
                unsigned int f = ld_coh32(&flags[lane & 15]);
                if (__all((int)(f >= tag))) break;
                if (++spins > (1 << 18)) { spins = 0; __threadfence(); }
            }
        }

        // ================= GEMM phase: HG slice = h_t @ w_slice^T ============
        q2bf afr[16];
        #pragma unroll
        for (int kt = 0; kt < 16; kt++) {
            afr[kt].q[0] = ld_coh(hbq_base + kt * 8);
            afr[kt].q[1] = ld_coh(hbq_base + kt * 8 + 1);
        }
        f32x4 a0 = {0,0,0,0}, a1 = {0,0,0,0}, a2 = {0,0,0,0};
        #pragma unroll
        for (int kt = 0; kt < 16; kt++) {
            bf16x8 b0 = *(const bf16x8*)&lw[((nj0    ) * 16 + l15) * WPITCH + kt * 32 + kq * 8];
            bf16x8 b1 = *(const bf16x8*)&lw[((nj0 + 1) * 16 + l15) * WPITCH + kt * 32 + kq * 8];
            bf16x8 b2 = *(const bf16x8*)&lw[((nj0 + 2) * 16 + l15) * WPITCH + kt * 32 + kq * 8];
            a0 = __builtin_amdgcn_mfma_f32_16x16x32_bf16(afr[kt].v, b0, a0, 0, 0, 0);
            a1 = __builtin_amdgcn_mfma_f32_16x16x32_bf16(afr[kt].v, b1, a1, 0, 0, 0);
            a2 = __builtin_amdgcn_mfma_f32_16x16x32_bf16(afr[kt].v, b2, a2, 0, 0, 0);
        }
        // ---- tagged HG publish: pair adjacent cols via shfl, even lanes store.
        // No drain / no flag / no barrier: data IS the sync.
        {
            int rowb = mt * 16 + kq * 4;
            int colb = n0 + nj0 * 16 + l15;
            #pragma unroll
            for (int r = 0; r < 4; r++) {
                float o0 = a0[r], o1 = a1[r], o2 = a2[r];
                float p0 = __shfl_xor(o0, 1);
                float p1 = __shfl_xor(o1, 1);
                float p2 = __shfl_xor(o2, 1);
                if (evenl) {
                    qword* rowp = HGP + (size_t)(rowb + r) * 768;
                    st_coh64(rowp + ((colb     ) >> 1), pack_hg(o0, p0, tag));
                    st_coh64(rowp + ((colb + 16) >> 1), pack_hg(o1, p1, tag));
                    st_coh64(rowp + ((colb + 32) >> 1), pack_hg(o2, p2, tag));
                }
            }
        }

        // ================= pointwise: poll tagged HG, LN x3 + gating =========
        qword qr0, qr1, qz0, qz1, qn0, qn1;
        {
            int spins = 0;
            for (;;) {
                qr0 = ld_coh(hg_mine);           qr1 = ld_coh(hg_mine + 1);
                qz0 = ld_coh(hg_mine + 256);     qz1 = ld_coh(hg_mine + 257);
                qn0 = ld_coh(hg_mine + 512);     qn1 = ld_coh(hg_mine + 513);
                bool ok = ((unsigned int)(qr0 >> 32) == tag) &
                          ((unsigned int)(qr1 >> 32) == tag) &
                          ((unsigned int)(qz0 >> 32) == tag) &
                          ((unsigned int)(qz1 >> 32) == tag) &
                          ((unsigned int)(qn0 >> 32) == tag) &
                          ((unsigned int)(qn1 >> 32) == tag);
                if (ok) break;
                if (++spins > (1 << 18)) { spins = 0; __threadfence(); }
            }
        }
        float hgr[4]  = {hg_lo(qr0), hg_hi(qr0), hg_lo(qr1), hg_hi(qr1)};
        float hgz[4]  = {hg_lo(qz0), hg_hi(qz0), hg_lo(qz1), hg_hi(qz1)};
        float hgnv[4] = {hg_lo(qn0), hg_hi(qn0), hg_lo(qn1), hg_hi(qn1)};

        float ar[4], az[4], hgn[4], xn[4];
        float sr = 0.f, ssr = 0.f, sz = 0.f, ssz = 0.f;
        #pragma unroll
        for (int j = 0; j < 4; j++) {
            ar[j]  = __bfloat162float(xr8.h[j]) + hgr[j] + bhr[j];
            az[j]  = __bfloat162float(xz8.h[j]) + hgz[j] + bhz[j];
            hgn[j] = hgnv[j] + bhn[j];
            xn[j]  = __bfloat162float(xn8.h[j]);
            sr += ar[j]; ssr += ar[j] * ar[j];
            sz += az[j]; ssz += az[j] * az[j];
        }
        // reduce 4 scalars over the 128 threads of this sample (waves 2sid,2sid+1)
        #pragma unroll
        for (int off = 32; off; off >>= 1) {
            sr += __shfl_down(sr, off); ssr += __shfl_down(ssr, off);
            sz += __shfl_down(sz, off); ssz += __shfl_down(ssz, off);
        }
        if (lane == 0) { sc[w * 4] = sr; sc[w * 4 + 1] = ssr; sc[w * 4 + 2] = sz; sc[w * 4 + 3] = ssz; }
        __syncthreads();
        {
            int w0 = sid * 2;
            sr  = sc[w0 * 4]     + sc[(w0 + 1) * 4];
            ssr = sc[w0 * 4 + 1] + sc[(w0 + 1) * 4 + 1];
            sz  = sc[w0 * 4 + 2] + sc[(w0 + 1) * 4 + 2];
            ssz = sc[w0 * 4 + 3] + sc[(w0 + 1) * 4 + 3];
        }
        __syncthreads();
        float mr = sr * inv, vr = ssr * inv - mr * mr, rstd_r = rsqrtf(vr + 1e-5f);
        float mz = sz * inv, vz = ssz * inv - mz * mz, rstd_z = rsqrtf(vz + 1e-5f);
        float rg[4], zg[4], an[4];
        float sn = 0.f, ssn = 0.f;
        #pragma unroll
        for (int j = 0; j < 4; j++) {
            rg[j] = 1.f / (1.f + __expf(-((ar[j] - mr) * rstd_r * wr[j] + br_[j])));
            zg[j] = 1.f / (1.f + __expf(-((az[j] - mz) * rstd_z * wz[j] + bz_[j])));
            an[j] = xn[j] + rg[j] * hgn[j];
            sn += an[j]; ssn += an[j] * an[j];
        }
        #pragma unroll
        for (int off = 32; off; off >>= 1) {
            sn += __shfl_down(sn, off); ssn += __shfl_down(ssn, off);
        }
        if (lane == 0) { sc[w * 4] = sn; sc[w * 4 + 1] = ssn; }
        __syncthreads();
        {
            int w0 = sid * 2;
            sn  = sc[w0 * 4]     + sc[(w0 + 1) * 4];
            ssn = sc[w0 * 4 + 1] + sc[(w0 + 1) * 4 + 1];
        }
        __syncthreads();
        float mn = sn * inv, vn = ssn * inv - mn * mn, rstd_n = rsqrtf(vn + 1e-5f);
        float hnew[4];
        qbf4 hbnew;
        #pragma unroll
        for (int j = 0; j < 4; j++) {
            float ng = tanhf((an[j] - mn) * rstd_n * wn[j] + bn_[j]);
            hnew[j] = (1.f - zg[j]) * ng + zg[j] * hf[j];
            hf[j] = hnew[j];
            hbnew.h[j] = __float2bfloat16(hnew[j]);
        }
        st_coh64((qword*)HB + (size_t)b * 128 + c, hbnew.q);  // 4 contiguous bf16
        // ---- HB publish: block-wide drain, then monotone flag = t+2 ----
        asm volatile("s_waitcnt vmcnt(0)" ::: "memory");
        __syncthreads();
        if (tid == 0) st_coh32(&flags[blk], (unsigned int)(t + 2));
        // out rows (private to this block, plain stores) — overlap next poll/GEMM
        *(f32x4*)(out + ((size_t)b * T_ + t) * H_ + 4 * c) =
            (f32x4){hnew[0], hnew[1], hnew[2], hnew[3]};
        if (t == T_ - 1) {
            *(f32x4*)(out + (size_t)B_ * T_ * H_ + b * H_ + 4 * c) =
                (f32x4){hnew[0], hnew[1], hnew[2], hnew[3]};
        }
    }
}

extern "C" void kernel_launch(void* const* d_in, const int* in_sizes, int n_in,
                              void* d_out, int out_size, void* d_ws, size_t ws_size,
                              hipStream_t stream)
{
    const float* x    = (const float*)d_in[0];
    const float* h    = (const float*)d_in[1];
    const float* w_ih = (const float*)d_in[2];
    const float* b_ih = (const float*)d_in[3];
    const float* w_hh = (const float*)d_in[4];
    const float* b_hh = (const float*)d_in[5];
    const float* lnrw = (const float*)d_in[6];
    const float* lnrb = (const float*)d_in[7];
    const float* lnzw = (const float*)d_in[8];
    const float* lnzb = (const float*)d_in[9];
    const float* lnnw = (const float*)d_in[10];
    const float* lnnb = (const float*)d_in[11];
    float* out = (float*)d_out;

    // ws layout (bytes), fits prior footprint 101,126,144:
    //   XG   bf16 [512][64][1536]    = 100,663,296 @ 0
    //   HGP  qword[64][768] (tagged) =     393,216 @ 100,663,296
    //   HB   bf16 [64][512]          =      65,536 @ 101,056,512
    //   FLG  u32  [16]               =          64 @ 101,122,048
    char* ws = (char*)d_ws;
    __hip_bfloat16* XG = (__hip_bfloat16*)ws;
    qword*         HGP = (qword*)(ws + 100663296);
    __hip_bfloat16* HB = (__hip_bfloat16*)(ws + 101056512);
    unsigned int*  FLG = (unsigned int*)(ws + 101122048);

    k0_init<<<128, 256, 0, stream>>>(h, HB, HGP, FLG);
    k1_xgemm<<<3072, 256, 0, stream>>>(x, w_ih, b_ih, XG);
    k2_recur<<<NBLK, 512, 0, stream>>>(h, w_hh, b_hh,
        lnrw, lnrb, lnzw, lnzb, lnnw, lnnb, XG, HGP, HB, FLG, out);
}

// Round 6
// 5674.670 us; speedup vs baseline: 1.3330x; 1.3330x over previous
//
#include <hip/hip_runtime.h>
#include <hip/hip_bf16.h>

// B=64, T=512, D=512, H=512, 3H=1536. fp32 I/O; bf16 MFMA operands.
#define B_ 64
#define T_ 512
#define D_ 512
#define H_ 512
#define G3 1536
#define NBLK 16          // persistent blocks: 96 gate-cols + 4 samples each

typedef float f32x4 __attribute__((ext_vector_type(4)));
typedef __bf16 bf16x8 __attribute__((ext_vector_type(8)));
typedef unsigned long long qword;

#define LDSP 56          // k1 LDS pitch
#define WPITCH 520       // persistent-kernel w-slice pitch (bf16 elems): breaks bank conflicts

union bfpack { bf16x8 v; __hip_bfloat16 h[8]; };
union qbf4 { qword q; __hip_bfloat16 h[4]; };    // 8B <-> 4 bf16

__device__ inline bf16x8 cvt8(const float* __restrict__ p) {
    float4 f0 = *(const float4*)p;
    float4 f1 = *(const float4*)(p + 4);
    bfpack u;
    u.h[0] = __float2bfloat16(f0.x); u.h[1] = __float2bfloat16(f0.y);
    u.h[2] = __float2bfloat16(f0.z); u.h[3] = __float2bfloat16(f0.w);
    u.h[4] = __float2bfloat16(f1.x); u.h[5] = __float2bfloat16(f1.y);
    u.h[6] = __float2bfloat16(f1.z); u.h[7] = __float2bfloat16(f1.w);
    return u.v;
}

// ---------------- K0: init HB (h bf16) + zero barrier counters ---------------
__global__ void k0_init(const float* __restrict__ h_in,
                        __hip_bfloat16* __restrict__ hb,
                        unsigned int* __restrict__ ctr) {
    int i = blockIdx.x * blockDim.x + threadIdx.x;
    if (i < B_ * H_) hb[i] = __float2bfloat16(h_in[i]);
    if (i < 1024)    ctr[i] = 0u;
}

// ---------------- K1: XG = x @ w_ih^T + b_ih (MFMA 128x128, bf16 out) --------
__global__ __launch_bounds__(256) void k1_xgemm(
    const float* __restrict__ X, const float* __restrict__ W,
    const float* __restrict__ bias, __hip_bfloat16* __restrict__ XG)
{
    __shared__ __align__(16) __hip_bfloat16 la[128 * LDSP];
    __shared__ __align__(16) __hip_bfloat16 lb[128 * LDSP];
    int tid = threadIdx.x, bx = blockIdx.x;
    int m0 = (bx / 12) * 128, n0 = (bx % 12) * 128;
    int wave = tid >> 6, lane = tid & 63;
    int wh = wave >> 1, ww = wave & 1;
    int l15 = lane & 15, kq = lane >> 4;

    f32x4 acc[4][4];
    #pragma unroll
    for (int i = 0; i < 4; i++)
        #pragma unroll
        for (int j = 0; j < 4; j++) acc[i][j] = (f32x4){0.f, 0.f, 0.f, 0.f};

    for (int kt = 0; kt < 16; ++kt) {
        int k0 = kt * 32;
        for (int s = tid; s < 512; s += 256) {
            int r = s >> 2, c = s & 3;
            *(bf16x8*)&la[r * LDSP + c * 8] = cvt8(&X[(size_t)(m0 + r) * D_ + k0 + c * 8]);
            *(bf16x8*)&lb[r * LDSP + c * 8] = cvt8(&W[(size_t)(n0 + r) * D_ + k0 + c * 8]);
        }
        __syncthreads();
        bf16x8 af[4], bq[4];
        #pragma unroll
        for (int i = 0; i < 4; i++)
            af[i] = *(const bf16x8*)&la[(wh * 64 + i * 16 + l15) * LDSP + kq * 8];
        #pragma unroll
        for (int j = 0; j < 4; j++)
            bq[j] = *(const bf16x8*)&lb[(ww * 64 + j * 16 + l15) * LDSP + kq * 8];
        #pragma unroll
        for (int i = 0; i < 4; i++)
            #pragma unroll
            for (int j = 0; j < 4; j++)
                acc[i][j] = __builtin_amdgcn_mfma_f32_16x16x32_bf16(af[i], bq[j], acc[i][j], 0, 0, 0);
        __syncthreads();
    }
    #pragma unroll
    for (int i = 0; i < 4; i++)
        #pragma unroll
        for (int j = 0; j < 4; j++)
            #pragma unroll
            for (int r = 0; r < 4; r++) {
                int m = m0 + wh * 64 + i * 16 + kq * 4 + r;
                int n = n0 + ww * 64 + j * 16 + l15;
                int b = m >> 9, t = m & 511;
                XG[((size_t)t * B_ + b) * G3 + n] = __float2bfloat16(acc[i][j][r] + bias[n]);
            }
}

// ---------------- K2: persistent recurrence kernel ---------------------------
// 16 blocks x 512 threads (R0 structure, proven correct). Barrier protocol
// minimized: release fence (wbl2) before arrive, RELAXED spin (no per-poll
// invalidate!), single acquire fence (inv) after wait. 2 wbl2 + 2 inv per
// step vs R0's 4+4 plus per-poll invs. Data accesses stay plain/cached.
__global__ __launch_bounds__(512, 1) void k2_recur(
    const float* __restrict__ h_in, const float* __restrict__ Whh,
    const float* __restrict__ b_hh,
    const float* __restrict__ lnrw, const float* __restrict__ lnrb,
    const float* __restrict__ lnzw, const float* __restrict__ lnzb,
    const float* __restrict__ lnnw, const float* __restrict__ lnnb,
    const __hip_bfloat16* __restrict__ XG,
    float* __restrict__ HG, __hip_bfloat16* __restrict__ HB,
    unsigned int* __restrict__ ctr, float* __restrict__ out)
{
    __shared__ __align__(16) __hip_bfloat16 lw[96 * WPITCH]; // 99,840 B
    __shared__ float sc[32];

    const int tid = threadIdx.x;
    const int blk = blockIdx.x;
    const int n0 = blk * 96;   // gate-column slice base
    const int s0 = blk * 4;    // pointwise sample base

    // --- one-time: stage w_hh slice fp32->bf16 into LDS (pitch WPITCH) ---
    for (int idx = tid; idx < 96 * 64; idx += 512) {
        int row = idx >> 6, ch = idx & 63;
        *(bf16x8*)&lw[row * WPITCH + ch * 8] = cvt8(&Whh[(size_t)(n0 + row) * H_ + ch * 8]);
    }

    // --- GEMM wave roles ---
    const int w = tid >> 6, lane = tid & 63;
    const int l15 = lane & 15, kq = lane >> 4;
    const int mt = w >> 1;             // m-tile 0..3 (rows mt*16+l15)
    const int nj0 = (w & 1) * 3;       // 3 n-tiles per wave

    // --- pointwise roles: sample sid, 4 CONTIGUOUS cols 4c..4c+3 ---
    const int sid = tid >> 7;          // 0..3
    const int c = tid & 127;
    const int b = s0 + sid;

    // per-thread constant preloads (stay in regs across the t-loop)
    float bhr[4], bhz[4], bhn[4], wr[4], br_[4], wz[4], bz_[4], wn[4], bn_[4], hf[4];
    #pragma unroll
    for (int j = 0; j < 4; j++) {
        int col = 4 * c + j;
        bhr[j] = b_hh[col];       bhz[j] = b_hh[512 + col]; bhn[j] = b_hh[1024 + col];
        wr[j] = lnrw[col]; br_[j] = lnrb[col];
        wz[j] = lnzw[col]; bz_[j] = lnzb[col];
        wn[j] = lnnw[col]; bn_[j] = lnnb[col];
        hf[j] = h_in[b * H_ + col];   // fp32 h shadow (this block owns sample b, cols 4c..4c+3)
    }
    __syncthreads();

    const float inv = 1.0f / 512.0f;
    const __hip_bfloat16* hrow = HB + (mt * 16 + l15) * H_ + kq * 8;
    const float* hg_mine = HG + (size_t)b * G3 + 4 * c;
    int dead = 0;    // hard-bail flag: guarantees termination, never fires normally

    for (int t = 0; t < T_; ++t) {
        // ---- XG preload for this step (plain cached loads; hide under GEMM)
        const qword* xgq = (const qword*)(XG + ((size_t)t * B_ + b) * G3) + c;
        qbf4 xr8, xz8, xn8;
        xr8.q = xgq[0];            // r-gate cols 4c..4c+3
        xz8.q = xgq[128];          // z-gate
        xn8.q = xgq[256];          // n-gate

        // ================= GEMM phase: HG slice = h_t @ w_slice^T ============
        bf16x8 afr[16];
        #pragma unroll
        for (int kt = 0; kt < 16; kt++) afr[kt] = *(const bf16x8*)(hrow + kt * 32);
        f32x4 a0 = {0,0,0,0}, a1 = {0,0,0,0}, a2 = {0,0,0,0};
        #pragma unroll
        for (int kt = 0; kt < 16; kt++) {
            bf16x8 b0 = *(const bf16x8*)&lw[((nj0    ) * 16 + l15) * WPITCH + kt * 32 + kq * 8];
            bf16x8 b1 = *(const bf16x8*)&lw[((nj0 + 1) * 16 + l15) * WPITCH + kt * 32 + kq * 8];
            bf16x8 b2 = *(const bf16x8*)&lw[((nj0 + 2) * 16 + l15) * WPITCH + kt * 32 + kq * 8];
            a0 = __builtin_amdgcn_mfma_f32_16x16x32_bf16(afr[kt], b0, a0, 0, 0, 0);
            a1 = __builtin_amdgcn_mfma_f32_16x16x32_bf16(afr[kt], b1, a1, 0, 0, 0);
            a2 = __builtin_amdgcn_mfma_f32_16x16x32_bf16(afr[kt], b2, a2, 0, 0, 0);
        }
        {
            int rowb = mt * 16 + kq * 4;
            int colb = n0 + nj0 * 16 + l15;
            #pragma unroll
            for (int r = 0; r < 4; r++) {
                HG[(rowb + r) * G3 + colb     ] = a0[r];
                HG[(rowb + r) * G3 + colb + 16] = a1[r];
                HG[(rowb + r) * G3 + colb + 32] = a2[r];
            }
        }
        // ---- barrier A: wbl2 (release) -> arrive -> relaxed spin -> inv ----
        __syncthreads();   // all threads' stores vmcnt-drained to L2
        if (tid == 0 && !dead) {
            __builtin_amdgcn_fence(__ATOMIC_RELEASE, "agent");    // buffer_wbl2
            __hip_atomic_fetch_add(&ctr[2 * t], 1u, __ATOMIC_RELAXED,
                                   __HIP_MEMORY_SCOPE_AGENT);
            int spins = 0;
            while (__hip_atomic_load(&ctr[2 * t], __ATOMIC_RELAXED,
                                     __HIP_MEMORY_SCOPE_AGENT) < NBLK) {
                if (++spins > (1 << 24)) { dead = 1; break; }
            }
            __builtin_amdgcn_fence(__ATOMIC_ACQUIRE, "agent");    // buffer_inv
        }
        __syncthreads();

        // ================= pointwise: LN x3 + gating for samples s0..s0+3 ====
        float4 hgr4 = *(const float4*)(hg_mine);
        float4 hgz4 = *(const float4*)(hg_mine + 512);
        float4 hgn4 = *(const float4*)(hg_mine + 1024);
        float hgr[4]  = {hgr4.x, hgr4.y, hgr4.z, hgr4.w};
        float hgz[4]  = {hgz4.x, hgz4.y, hgz4.z, hgz4.w};
        float hgnv[4] = {hgn4.x, hgn4.y, hgn4.z, hgn4.w};

        float ar[4], az[4], hgn[4], xn[4];
        float sr = 0.f, ssr = 0.f, sz = 0.f, ssz = 0.f;
        #pragma unroll
        for (int j = 0; j < 4; j++) {
            ar[j]  = __bfloat162float(xr8.h[j]) + hgr[j] + bhr[j];
            az[j]  = __bfloat162float(xz8.h[j]) + hgz[j] + bhz[j];
            hgn[j] = hgnv[j] + bhn[j];
            xn[j]  = __bfloat162float(xn8.h[j]);
            sr += ar[j]; ssr += ar[j] * ar[j];
            sz += az[j]; ssz += az[j] * az[j];
        }
        // reduce 4 scalars over the 128 threads of this sample (waves 2sid,2sid+1)
        #pragma unroll
        for (int off = 32; off; off >>= 1) {
            sr += __shfl_down(sr, off); ssr += __shfl_down(ssr, off);
            sz += __shfl_down(sz, off); ssz += __shfl_down(ssz, off);
        }
        if (lane == 0) { sc[w * 4] = sr; sc[w * 4 + 1] = ssr; sc[w * 4 + 2] = sz; sc[w * 4 + 3] = ssz; }
        __syncthreads();
        {
            int w0 = sid * 2;
            sr  = sc[w0 * 4]     + sc[(w0 + 1) * 4];
            ssr = sc[w0 * 4 + 1] + sc[(w0 + 1) * 4 + 1];
            sz  = sc[w0 * 4 + 2] + sc[(w0 + 1) * 4 + 2];
            ssz = sc[w0 * 4 + 3] + sc[(w0 + 1) * 4 + 3];
        }
        __syncthreads();
        float mr = sr * inv, vr = ssr * inv - mr * mr, rstd_r = rsqrtf(vr + 1e-5f);
        float mz = sz * inv, vz = ssz * inv - mz * mz, rstd_z = rsqrtf(vz + 1e-5f);
        float rg[4], zg[4], an[4];
        float sn = 0.f, ssn = 0.f;
        #pragma unroll
        for (int j = 0; j < 4; j++) {
            rg[j] = 1.f / (1.f + __expf(-((ar[j] - mr) * rstd_r * wr[j] + br_[j])));
            zg[j] = 1.f / (1.f + __expf(-((az[j] - mz) * rstd_z * wz[j] + bz_[j])));
            an[j] = xn[j] + rg[j] * hgn[j];
            sn += an[j]; ssn += an[j] * an[j];
        }
        #pragma unroll
        for (int off = 32; off; off >>= 1) {
            sn += __shfl_down(sn, off); ssn += __shfl_down(ssn, off);
        }
        if (lane == 0) { sc[w * 4] = sn; sc[w * 4 + 1] = ssn; }
        __syncthreads();
        {
            int w0 = sid * 2;
            sn  = sc[w0 * 4]     + sc[(w0 + 1) * 4];
            ssn = sc[w0 * 4 + 1] + sc[(w0 + 1) * 4 + 1];
        }
        __syncthreads();
        float mn = sn * inv, vn = ssn * inv - mn * mn, rstd_n = rsqrtf(vn + 1e-5f);
        float hnew[4];
        qbf4 hbnew;
        #pragma unroll
        for (int j = 0; j < 4; j++) {
            float ng = tanhf((an[j] - mn) * rstd_n * wn[j] + bn_[j]);
            hnew[j] = (1.f - zg[j]) * ng + zg[j] * hf[j];
            hf[j] = hnew[j];
            hbnew.h[j] = __float2bfloat16(hnew[j]);
        }
        *((qword*)HB + (size_t)b * 128 + c) = hbnew.q;   // 4 contiguous bf16, plain store
        // ---- barrier B: wbl2 (release) -> arrive -> relaxed spin -> inv ----
        __syncthreads();
        if (tid == 0 && !dead) {
            __builtin_amdgcn_fence(__ATOMIC_RELEASE, "agent");
            __hip_atomic_fetch_add(&ctr[2 * t + 1], 1u, __ATOMIC_RELAXED,
                                   __HIP_MEMORY_SCOPE_AGENT);
            int spins = 0;
            while (__hip_atomic_load(&ctr[2 * t + 1], __ATOMIC_RELAXED,
                                     __HIP_MEMORY_SCOPE_AGENT) < NBLK) {
                if (++spins > (1 << 24)) { dead = 1; break; }
            }
            __builtin_amdgcn_fence(__ATOMIC_ACQUIRE, "agent");
        }
        __syncthreads();
        // out rows (private to this block, plain stores) — after barrier,
        // overlaps next step's GEMM
        *(f32x4*)(out + ((size_t)b * T_ + t) * H_ + 4 * c) =
            (f32x4){hnew[0], hnew[1], hnew[2], hnew[3]};
        if (t == T_ - 1) {
            *(f32x4*)(out + (size_t)B_ * T_ * H_ + b * H_ + 4 * c) =
                (f32x4){hnew[0], hnew[1], hnew[2], hnew[3]};
        }
    }
}

extern "C" void kernel_launch(void* const* d_in, const int* in_sizes, int n_in,
                              void* d_out, int out_size, void* d_ws, size_t ws_size,
                              hipStream_t stream)
{
    const float* x    = (const float*)d_in[0];
    const float* h    = (const float*)d_in[1];
    const float* w_ih = (const float*)d_in[2];
    const float* b_ih = (const float*)d_in[3];
    const float* w_hh = (const float*)d_in[4];
    const float* b_hh = (const float*)d_in[5];
    const float* lnrw = (const float*)d_in[6];
    const float* lnrb = (const float*)d_in[7];
    const float* lnzw = (const float*)d_in[8];
    const float* lnzb = (const float*)d_in[9];
    const float* lnnw = (const float*)d_in[10];
    const float* lnnb = (const float*)d_in[11];
    float* out = (float*)d_out;

    // ws layout (bytes):
    //   XG  bf16 [512][64][1536] = 100,663,296 @ 0
    //   HG  f32  [64][1536]      =     393,216 @ 100,663,296
    //   HB  bf16 [64][512]       =      65,536 @ 101,056,512
    //   CTR u32  [1024]          =       4,096 @ 101,122,048
    char* ws = (char*)d_ws;
    __hip_bfloat16* XG = (__hip_bfloat16*)ws;
    float*          HG = (float*)(ws + 100663296);
    __hip_bfloat16* HB = (__hip_bfloat16*)(ws + 101056512);
    unsigned int*  CTR = (unsigned int*)(ws + 101122048);

    k0_init<<<128, 256, 0, stream>>>(h, HB, CTR);
    k1_xgemm<<<3072, 256, 0, stream>>>(x, w_ih, b_ih, XG);
    k2_recur<<<NBLK, 512, 0, stream>>>(h, w_hh, b_hh,
        lnrw, lnrb, lnzw, lnzb, lnnw, lnnb, XG, HG, HB, CTR, out);
}